// Round 6
// baseline (103.641 us; speedup 1.0000x reference)
//
#include <hip/hip_runtime.h>
#include <hip/hip_bf16.h>
#include <math.h>

#define MUL 8
#define HID 16
#define NB 10

typedef short short8 __attribute__((ext_vector_type(8)));
typedef float floatx4 __attribute__((ext_vector_type(4)));

__device__ __forceinline__ unsigned short f2bf(float x) {
    unsigned u = __float_as_uint(x);
    return (unsigned short)((u + 0x7fffu + ((u >> 16) & 1u)) >> 16);  // RNE
}

// pack two floats -> packed bf16x2 (lo = first arg), RNE
__device__ __forceinline__ unsigned pack2(float lo, float hi) {
#if __has_builtin(__builtin_amdgcn_cvt_pk_bf16_f32)
    typedef __bf16 bf2 __attribute__((ext_vector_type(2)));
    bf2 p = __builtin_amdgcn_cvt_pk_bf16_f32(lo, hi);
    return *reinterpret_cast<unsigned*>(&p);
#else
    return (unsigned)f2bf(lo) | ((unsigned)f2bf(hi) << 16);
#endif
}

// splice 16-bit fields of two words: sel 0x05040100 -> (w0.lo | w1.lo<<16),
// 0x07060302 -> (w0.hi | w1.hi<<16)
__device__ __forceinline__ unsigned perm_pair(unsigned w1, unsigned w0, unsigned sel) {
#if __has_builtin(__builtin_amdgcn_perm)
    return __builtin_amdgcn_perm(w1, w0, sel);
#else
    if (sel == 0x05040100u) return (w0 & 0xffffu) | (w1 << 16);
    return (w0 >> 16) | (w1 & 0xffff0000u);
#endif
}

#define UNP(u, lo, hi) { lo = __uint_as_float((u) << 16); hi = __uint_as_float((u) & 0xffff0000u); }

// ws layout (floats): [0..511] W2r scaled | [512..671] W1s | [672..] Xb (16B-aligned @2688B)
// Kernel 1: bf16-pack the node table; block 0 additionally builds scaled
// weights and zeroes out[0].
__global__ __launch_bounds__(256) void conv_prep_kernel(
    const float* __restrict__ X, unsigned* __restrict__ Xb, int nPack,
    const float* __restrict__ W1, const float* __restrict__ W2,
    float* __restrict__ ws, float* __restrict__ out)
{
    int i = blockIdx.x * 256 + threadIdx.x;
    if (i < nPack) {
        float2 f = ((const float2*)X)[i];
        Xb[i] = pack2(f.x, f.y);
    }
    if (blockIdx.x == 0) {
        int t = threadIdx.x;
        if (t == 0) out[0] = 0.0f;
        const float pw0 = 0.25f;            // sqrt(1/16)
        const float pw1 = 0.43301270189f;   // sqrt(3/16)
        const float i3  = 0.57735026919f;   // 1/sqrt(3)
#pragma unroll
        for (int k = t; k < HID * 32; k += 256) {
            int j  = k >> 5;
            int cu = k & 31;
            int c  = cu >> 3;
            float gs = (c < 2) ? pw0 : ((c == 2) ? pw1 : pw1 * i3);
            const float* p = W2 + j * 256 + cu * 8;
            float s = 0.0f;
#pragma unroll
            for (int v = 0; v < 8; ++v) s += p[v];
            ws[k] = s * 0.0625f * gs;       // 1/sqrt(HID) * 1/sqrt(NUM_NEIGHBORS)
        }
        if (t < NB * HID) ws[512 + t] = W1[t] * 1.41421356237f;
    }
}

// Kernel 2: each wave handles 128 edges (2 per lane, adjacent -> adjacent kk
// slots -> all LDS writes are packed b32 pairs). M += h x f via 8 MFMAs
// (K=128); weights applied once per wave in the epilogue.
__global__ __launch_bounds__(256, 3) void edge_kernel(
    const unsigned* __restrict__ Xb,   // N x 16 uints (32 bf16)
    const float* __restrict__ EV,      // E x 3
    const int*   __restrict__ SRC,     // E
    const float* __restrict__ W2r,     // 16 x 32 scaled
    const float* __restrict__ W1s,     // 10 x 16 scaled
    float* __restrict__ out, int E)
{
    __shared__ short A_lds[4][16][128];  // [wave][j][kk], xor-swizzled chunks
    __shared__ short B_lds[4][32][128];  // [wave][n][kk]
    int tid = threadIdx.x;
    int w = tid >> 6, l = tid & 63;
    int ebase = blockIdx.x * 512 + w * 128 + 2 * l;   // even
    bool v0 = (ebase < E), v1 = (ebase + 1 < E);
    int ec0 = v0 ? ebase : 0;

    int2 sp;
    float ex0, ey0, ez0, ex1, ey1, ez1;
    if (v1) {
        sp = *(const int2*)(SRC + ebase);
        const float* evp = EV + 3 * ebase;
        float2 a = *(const float2*)evp;
        float2 b = *(const float2*)(evp + 2);
        float2 c = *(const float2*)(evp + 4);
        ex0 = a.x; ey0 = a.y; ez0 = b.x;
        ex1 = b.y; ey1 = c.x; ez1 = c.y;
    } else {
        sp.x = SRC[ec0]; sp.y = sp.x;
        ex0 = EV[3 * ec0]; ey0 = EV[3 * ec0 + 1]; ez0 = EV[3 * ec0 + 2];
        ex1 = ex0; ey1 = ey0; ez1 = ez0;   // invalid edge masked via fa/fb=0
    }

    // gathers for both edges (in flight while basis computes)
    const uint4* xp0 = (const uint4*)(Xb + (size_t)sp.x * 16);
    const uint4* xp1 = (const uint4*)(Xb + (size_t)sp.y * 16);
    uint4 p0 = xp0[0], p1 = xp0[1], p2 = xp0[2], p3 = xp0[3];
    uint4 r0 = xp1[0], r1 = xp1[1], r2 = xp1[2], r3 = xp1[3];

    float rr0 = sqrtf(ex0 * ex0 + ey0 * ey0 + ez0 * ez0);
    float ir0 = 1.0f / rr0;
    float ux0 = ex0 * ir0, uy0 = ey0 * ir0, uz0 = ez0 * ir0;
    float U0 = ux0 + uy0 + uz0;
    float rr1 = sqrtf(ex1 * ex1 + ey1 * ey1 + ez1 * ez1);
    float ir1 = 1.0f / rr1;
    float ux1 = ex1 * ir1, uy1 = ey1 * ir1, uz1 = ez1 * ir1;
    float U1 = ux1 + uy1 + uz1;

    // 2-sparse soft one-hot for both edges
    const float inv_step = 11.0f / 3.0f;
    float q0f = rr0 * inv_step, q1f = rr1 * inv_step;
    int qi0 = (int)floorf(q0f), qi1 = (int)floorf(q1f);
    int ia0 = qi0 - 1, ib0 = qi0, ia1 = qi1 - 1, ib1 = qi1;
    float da0 = q0f - (float)(ia0 + 1), db0 = q0f - (float)(ib0 + 1);
    float da1 = q1f - (float)(ia1 + 1), db1 = q1f - (float)(ib1 + 1);
    float na0 = 1.0f - da0 * da0, nb0 = 1.0f - db0 * db0;
    float na1 = 1.0f - da1 * da1, nb1 = 1.0f - db1 * db1;
    float fa0 = ((ia0 >= 0) & (ia0 < NB) & v0) ? 1.14136f * __expf(2.0f - 2.0f / na0) : 0.0f;
    float fb0 = ((ib0 >= 0) & (ib0 < NB) & v0) ? 1.14136f * __expf(2.0f - 2.0f / nb0) : 0.0f;
    float fa1 = ((ia1 >= 0) & (ia1 < NB) & v1) ? 1.14136f * __expf(2.0f - 2.0f / na1) : 0.0f;
    float fb1 = ((ib1 >= 0) & (ib1 < NB) & v1) ? 1.14136f * __expf(2.0f - 2.0f / nb1) : 0.0f;
    const float* ra0 = W1s + min(max(ia0, 0), NB - 1) * HID;
    const float* rb0 = W1s + min(max(ib0, 0), NB - 1) * HID;
    const float* ra1 = W1s + min(max(ia1, 0), NB - 1) * HID;
    const float* rb1 = W1s + min(max(ib1, 0), NB - 1) * HID;

    int chunk = l >> 2;       // kk chunk (0..15) this lane's pair lands in
    int colu  = l & 3;        // uint column within chunk

    // A rows: h for both edges, packed pair per write
#pragma unroll
    for (int j = 0; j < HID; ++j) {
        float a0 = fa0 * ra0[j] + fb0 * rb0[j]; a0 = (a0 > 0.0f) ? a0 : 0.0f;
        float a1 = fa1 * ra1[j] + fb1 * rb1[j]; a1 = (a1 > 0.0f) ? a1 : 0.0f;
        ((unsigned*)&A_lds[w][j][0])[((chunk ^ (j & 7)) << 2) | colu] = pack2(a0, a1);
    }

    // B rows 0..7 (s): bf16 bits straight from the gathered words via v_perm
    unsigned sw0[4] = {p0.x, p0.y, p0.z, p0.w};
    unsigned sw1[4] = {r0.x, r0.y, r0.z, r0.w};
#pragma unroll
    for (int u = 0; u < 8; ++u) {
        unsigned pr = perm_pair(sw1[u >> 1], sw0[u >> 1],
                                (u & 1) ? 0x07060302u : 0x05040100u);
        ((unsigned*)&B_lds[w][u][0])[((chunk ^ (u & 7)) << 2) | colu] = pr;
    }

    // s floats (for s*U rows)
    float s0[8], s1[8];
    UNP(p0.x, s0[0], s0[1]); UNP(p0.y, s0[2], s0[3]);
    UNP(p0.z, s0[4], s0[5]); UNP(p0.w, s0[6], s0[7]);
    UNP(r0.x, s1[0], s1[1]); UNP(r0.y, s1[2], s1[3]);
    UNP(r0.z, s1[4], s1[5]); UNP(r0.w, s1[6], s1[7]);

    // vector features
    unsigned vw0[12] = {p1.x, p1.y, p1.z, p1.w, p2.x, p2.y, p2.z, p2.w,
                        p3.x, p3.y, p3.z, p3.w};
    unsigned vw1[12] = {r1.x, r1.y, r1.z, r1.w, r2.x, r2.y, r2.z, r2.w,
                        r3.x, r3.y, r3.z, r3.w};
    float va0[24], va1[24];
#pragma unroll
    for (int k = 0; k < 12; ++k) {
        UNP(vw0[k], va0[2 * k], va0[2 * k + 1]);
        UNP(vw1[k], va1[2 * k], va1[2 * k + 1]);
    }
#pragma unroll
    for (int u = 0; u < 8; ++u) {
        float vx0 = va0[3 * u], vy0 = va0[3 * u + 1], vz0 = va0[3 * u + 2];
        float vx1 = va1[3 * u], vy1 = va1[3 * u + 1], vz1 = va1[3 * u + 2];
        float d0 = vx0 * ux0 + vy0 * uy0 + vz0 * uz0;
        float d1 = vx1 * ux1 + vy1 * uy1 + vz1 * uz1;
        float V0 = vx0 + vy0 + vz0;
        float V1 = vx1 + vy1 + vz1;
        int n1 = 8 + u, n2 = 16 + u, n3 = 24 + u;
        ((unsigned*)&B_lds[w][n1][0])[((chunk ^ (n1 & 7)) << 2) | colu] = pack2(d0, d1);
        ((unsigned*)&B_lds[w][n2][0])[((chunk ^ (n2 & 7)) << 2) | colu] = pack2(s0[u] * U0, s1[u] * U1);
        ((unsigned*)&B_lds[w][n3][0])[((chunk ^ (n3 & 7)) << 2) | colu] = pack2(V0, V1);
    }
    __syncthreads();

    // fragments (K=128 -> 4 k-blocks x 2 n-halves): A[m=ln][k], B[k][n]
    int ln = l & 15, q = l >> 4;
    floatx4 acc0 = {0.f, 0.f, 0.f, 0.f}, acc1 = {0.f, 0.f, 0.f, 0.f};
#pragma unroll
    for (int i = 0; i < 4; ++i) {
        int c = 4 * i + q;
        int so = ((c ^ (ln & 7)) << 3);
        short8 af = *(const short8*)&A_lds[w][ln][so];
        short8 b0 = *(const short8*)&B_lds[w][ln][so];
        short8 b1 = *(const short8*)&B_lds[w][ln + 16][so];  // (ln+16)&7 == ln&7
        acc0 = __builtin_amdgcn_mfma_f32_16x16x32_bf16(af, b0, acc0, 0, 0, 0);
        acc1 = __builtin_amdgcn_mfma_f32_16x16x32_bf16(af, b1, acc1, 0, 0, 0);
    }

    // epilogue: elementwise W . M once per wave.
    // C/D: col = lane&15 (=n), row = (lane>>4)*4 + reg  (m89-verified)
    float p = 0.0f;
#pragma unroll
    for (int i = 0; i < 4; ++i) {
        int row = q * 4 + i;
        p += acc0[i] * W2r[row * 32 + ln] + acc1[i] * W2r[row * 32 + 16 + ln];
    }
#pragma unroll
    for (int off = 32; off > 0; off >>= 1)
        p += __shfl_down(p, off, 64);

    __shared__ float wsum[4];
    if (l == 0) wsum[w] = p;
    __syncthreads();
    if (tid == 0)
        atomicAdd(out, wsum[0] + wsum[1] + wsum[2] + wsum[3]);
}

// Fallback (ws too small for bf16 table): prep-only + per-edge f32 contraction.
__global__ __launch_bounds__(256, 6) void edge_kernel_f32(
    const float* __restrict__ X, const float* __restrict__ EV,
    const int* __restrict__ SRC, const float* __restrict__ W2r,
    const float* __restrict__ W1s, float* __restrict__ out, int E)
{
    int tid = threadIdx.x;
    int e = blockIdx.x * 256 + tid;
    float contrib = 0.0f;
    if (e < E) {
        int si = SRC[e];
        const float4* xp = (const float4*)(X + (size_t)si * 32);
        float4 x[8];
#pragma unroll
        for (int k = 0; k < 8; ++k) x[k] = xp[k];
        float ex = EV[3 * e], ey = EV[3 * e + 1], ez = EV[3 * e + 2];
        float r = sqrtf(ex * ex + ey * ey + ez * ez);
        float ir = 1.0f / r;
        float ux = ex * ir, uy = ey * ir, uz = ez * ir;
        float U = ux + uy + uz;
        const float inv_step = 11.0f / 3.0f;
        float qq = r * inv_step;
        int qi = (int)floorf(qq);
        int ia = qi - 1, ib = qi;
        float diffa = qq - (float)(ia + 1), diffb = qq - (float)(ib + 1);
        float dena = 1.0f - diffa * diffa, denb = 1.0f - diffb * diffb;
        float fa = ((ia >= 0) & (ia < NB)) ? 1.14136f * __expf(2.0f - 2.0f / dena) : 0.0f;
        float fb = ((ib >= 0) & (ib < NB)) ? 1.14136f * __expf(2.0f - 2.0f / denb) : 0.0f;
        const float* ra = W1s + min(max(ia, 0), NB - 1) * HID;
        const float* rb = W1s + min(max(ib, 0), NB - 1) * HID;
        float h[HID];
#pragma unroll
        for (int j = 0; j < HID; ++j) {
            float a = fa * ra[j] + fb * rb[j];
            h[j] = (a > 0.0f) ? a : 0.0f;
        }
        float s[8] = {x[0].x, x[0].y, x[0].z, x[0].w, x[1].x, x[1].y, x[1].z, x[1].w};
        float vv[24];
#pragma unroll
        for (int k = 0; k < 6; ++k) {
            vv[4 * k + 0] = x[2 + k].x; vv[4 * k + 1] = x[2 + k].y;
            vv[4 * k + 2] = x[2 + k].z; vv[4 * k + 3] = x[2 + k].w;
        }
        float d[8], V[8];
#pragma unroll
        for (int u = 0; u < 8; ++u) {
            float vx = vv[3 * u], vy = vv[3 * u + 1], vz = vv[3 * u + 2];
            d[u] = vx * ux + vy * uy + vz * uz;
            V[u] = vx + vy + vz;
        }
        float acc = 0.0f;
#pragma unroll
        for (int j = 0; j < HID; ++j) {
            const float* wt = W2r + j * 32;
            float A = 0, B = 0, C = 0, D = 0;
#pragma unroll
            for (int u = 0; u < 8; ++u) {
                A += wt[u] * s[u]; B += wt[8 + u] * d[u];
                C += wt[16 + u] * s[u]; D += wt[24 + u] * V[u];
            }
            acc += h[j] * (A + B + U * C + D);
        }
        contrib = acc;
    }
#pragma unroll
    for (int off = 32; off > 0; off >>= 1)
        contrib += __shfl_down(contrib, off, 64);
    __shared__ float wsum[4];
    int lane = tid & 63, w = tid >> 6;
    if (lane == 0) wsum[w] = contrib;
    __syncthreads();
    if (tid == 0)
        atomicAdd(out, wsum[0] + wsum[1] + wsum[2] + wsum[3]);
}

extern "C" void kernel_launch(void* const* d_in, const int* in_sizes, int n_in,
                              void* d_out, int out_size, void* d_ws, size_t ws_size,
                              hipStream_t stream) {
    const float* X   = (const float*)d_in[0];
    const float* EV  = (const float*)d_in[1];
    const float* W1  = (const float*)d_in[2];
    const float* W2  = (const float*)d_in[3];
    const int*   SRC = (const int*)d_in[4];
    int E = in_sizes[4];
    int N = in_sizes[0] / 32;

    float* ws  = (float*)d_ws;
    float* out = (float*)d_out;

    size_t need = 2688 + (size_t)N * 64;
    if (ws_size >= need) {
        unsigned* Xb = (unsigned*)((char*)d_ws + 2688);
        int nPack = N * 16;
        int cblocks = (nPack + 255) / 256;
        conv_prep_kernel<<<cblocks, 256, 0, stream>>>(X, Xb, nPack, W1, W2, ws, out);
        int eblocks = (E + 511) / 512;
        edge_kernel<<<eblocks, 256, 0, stream>>>(Xb, EV, SRC, ws, ws + 512, out, E);
    } else {
        conv_prep_kernel<<<1, 256, 0, stream>>>(X, (unsigned*)nullptr, 0, W1, W2, ws, out);
        int blocks = (E + 255) / 256;
        edge_kernel_f32<<<blocks, 256, 0, stream>>>(X, EV, SRC, ws, ws + 512, out, E);
    }
}